// Round 22
// baseline (136.462 us; speedup 1.0000x reference)
//
#include <hip/hip_runtime.h>
#include <hip/hip_bf16.h>
#include <cstdint>

#define BB 64
#define TT 200
#define KN 2000
#define VV 128
#define NGRU 16   // GRU blocks; 256 thr = 4 waves, each wave owns 2 col-tiles

typedef __attribute__((ext_vector_type(8))) short bf16x8;
typedef __attribute__((ext_vector_type(4))) float f32x4;
typedef _Float16 half8 __attribute__((ext_vector_type(8)));

// ws layout (floats): pd[384]@0, pr[384]@384, uc[128]@768, ud[128]@896, ur[128]@1024

// r11/r13: IEEE divides were the gate chain; rcp forms (~1ulp) are fine.
__device__ __forceinline__ float sigm(float x) {
    return __builtin_amdgcn_rcpf(1.f + __expf(-x));
}
__device__ __forceinline__ float tanh_f(float x) {
    float e = __expf(2.f * x);
    return 1.f - 2.f * __builtin_amdgcn_rcpf(e + 1.f);
}

// r17: LDS spin barriers lose 3x to s_barrier. r20/r21: per-CU issue-bound,
// chain depth neutral. r22 theory: LDS pipe is the binding per-CU resource
// (8 waves x redundant A-frag reads ~500-650cy/step) -> halve wave count,
// double cols/wave (A-frags shared across a wave's two tiles).
__device__ __forceinline__ void soft_barrier() {
    asm volatile("s_waitcnt lgkmcnt(0)" ::: "memory");
    __builtin_amdgcn_s_barrier();
    __builtin_amdgcn_sched_barrier(0);
}

// ---------------- precompute: small projection vectors (once, chip-wide) -----
__global__ void pre_kernel(const float* __restrict__ v_d, const float* __restrict__ v_r,
                           const float* __restrict__ v_c, const float* __restrict__ W_ih,
                           const float* __restrict__ W2a, float* __restrict__ ws)
{
    int g = blockIdx.x * 256 + threadIdx.x;   // grid 2 x 256 = 512 threads
    float* pd = ws;
    float* pr = ws + 384;
    float* uc = ws + 768;
    float* ud = ws + 896;
    float* ur = ws + 1024;
    if (g < 384) {
        float a = 0.f, b = 0.f;
        for (int k = 0; k < VV; ++k) {
            a = fmaf(W_ih[g * 256 + k], v_d[k], a);
            b = fmaf(W_ih[g * 256 + VV + k], v_r[k], b);
        }
        pd[g] = a; pr[g] = b;
    }
    if (g < VV) {
        float a = 0.f, b = 0.f, c = 0.f;
        for (int k = 0; k < VV; ++k) {
            a = fmaf(W2a[g * 384 + k], v_c[k], a);
            b = fmaf(W2a[g * 384 + VV + k], v_d[k], b);
            c = fmaf(W2a[g * 384 + 2 * VV + k], v_r[k], c);
        }
        uc[g] = a; ud[g] = b; ur[g] = c;
    }
}

__device__ __forceinline__ half8 load_cvt8h(const float* p) {
    float4 a = *(const float4*)p;
    float4 c = *(const float4*)(p + 4);
    half8 r;
    r[0] = (_Float16)a.x; r[1] = (_Float16)a.y; r[2] = (_Float16)a.z; r[3] = (_Float16)a.w;
    r[4] = (_Float16)c.x; r[5] = (_Float16)c.y; r[6] = (_Float16)c.z; r[7] = (_Float16)c.w;
    return r;
}

// ---------------- fused: blocks 0-15 GRU (4 rows, 4 waves x 2 col-tiles), ----
// ---------------- blocks 16-79 mem scan (256 thr) ----------------------------
__global__ __launch_bounds__(256, 1) void fused_kernel(
    const int* __restrict__ c_seq, const int* __restrict__ d_seq,
    const float* __restrict__ r_seq, const float* __restrict__ D_emb,
    const float* __restrict__ Whh, const float* __restrict__ bih,
    const float* __restrict__ bhh, const float* __restrict__ W2b,
    const float* __restrict__ b2a, const float* __restrict__ b2b,
    const float* __restrict__ ws, float* __restrict__ C_out,
    float* __restrict__ h_out)
{
    __shared__ __align__(16) _Float16 H_half[16 * 136];   // rows ≢0 mod 4 stay 0
    __shared__ __align__(8) float gam4[TT * 4], r4[TT * 4];  // [t][rr]
    __shared__ __align__(16) float C[KN];
    __shared__ float gam_row[TT], r_row[TT], n_row[TT];
    __shared__ int c_row[TT + 1];

    int tid = threadIdx.x;

    if (blockIdx.x < NGRU) {
        // ================= GRU path: 4 batch rows =================
        int b0 = blockIdx.x * 4;
        const float* pd = ws;
        const float* pr = ws + 384;

        for (int i = tid; i < TT * 4; i += 256) {
            int t = i >> 2, rr = i & 3;
            gam4[i] = D_emb[d_seq[(b0 + rr) * TT + t]];
            r4[i] = r_seq[(b0 + rr) * TT + t];
        }
        for (int i = tid; i < 16 * 136; i += 256) H_half[i] = (_Float16)0.f;

        int wid = tid >> 6, l = tid & 63;
        int cl = l & 15, gq = l >> 4;
        int c1 = wid * 32 + cl;      // first output col
        int c2 = c1 + 16;            // second output col
        // batch row this lane owns: b0+gq, at MFMA row gq*4 (acc elem 0).

        // B-fragments for BOTH col-tiles: 24 half8 = 96 regs, resident
        const float* wr1 = Whh + (size_t)c1 * VV + gq * 8;
        const float* wz1 = Whh + (size_t)(c1 + 128) * VV + gq * 8;
        const float* wn1 = Whh + (size_t)(c1 + 256) * VV + gq * 8;
        const float* wr2 = Whh + (size_t)c2 * VV + gq * 8;
        const float* wz2 = Whh + (size_t)(c2 + 128) * VV + gq * 8;
        const float* wn2 = Whh + (size_t)(c2 + 256) * VV + gq * 8;
        half8 br10 = load_cvt8h(wr1),      br11 = load_cvt8h(wr1 + 32),
              br12 = load_cvt8h(wr1 + 64), br13 = load_cvt8h(wr1 + 96);
        half8 bz10 = load_cvt8h(wz1),      bz11 = load_cvt8h(wz1 + 32),
              bz12 = load_cvt8h(wz1 + 64), bz13 = load_cvt8h(wz1 + 96);
        half8 bn10 = load_cvt8h(wn1),      bn11 = load_cvt8h(wn1 + 32),
              bn12 = load_cvt8h(wn1 + 64), bn13 = load_cvt8h(wn1 + 96);
        half8 br20 = load_cvt8h(wr2),      br21 = load_cvt8h(wr2 + 32),
              br22 = load_cvt8h(wr2 + 64), br23 = load_cvt8h(wr2 + 96);
        half8 bz20 = load_cvt8h(wz2),      bz21 = load_cvt8h(wz2 + 32),
              bz22 = load_cvt8h(wz2 + 64), bz23 = load_cvt8h(wz2 + 96);
        half8 bn20 = load_cvt8h(wn2),      bn21 = load_cvt8h(wn2 + 32),
              bn22 = load_cvt8h(wn2 + 64), bn23 = load_cvt8h(wn2 + 96);

        // per-col gi fold scalars
        float gr_pd1 = pd[c1],       gr_pr1 = pr[c1],       gr_b1 = bih[c1] + bhh[c1];
        float gz_pd1 = pd[c1 + 128], gz_pr1 = pr[c1 + 128], gz_b1 = bih[c1 + 128] + bhh[c1 + 128];
        float gn_pd1 = pd[c1 + 256], gn_pr1 = pr[c1 + 256], gn_b1 = bih[c1 + 256];
        float gn_bh1 = bhh[c1 + 256];
        float gr_pd2 = pd[c2],       gr_pr2 = pr[c2],       gr_b2 = bih[c2] + bhh[c2];
        float gz_pd2 = pd[c2 + 128], gz_pr2 = pr[c2 + 128], gz_b2 = bih[c2 + 128] + bhh[c2 + 128];
        float gn_pd2 = pd[c2 + 256], gn_pr2 = pr[c2 + 256], gn_b2 = bih[c2 + 256];
        float gn_bh2 = bhh[c2 + 256];

        float h1 = 0.f, h2 = 0.f;
        __syncthreads();   // setup barrier

        float* hp = h_out + ((size_t)(b0 + gq) * TT) * VV;

        for (int t = 0; t < TT; ++t) {
            asm volatile("" : "+v"(br10), "+v"(br11), "+v"(br12), "+v"(br13),
                              "+v"(bz10), "+v"(bz11), "+v"(bz12), "+v"(bz13),
                              "+v"(bn10), "+v"(bn11), "+v"(bn12), "+v"(bn13));
            asm volatile("" : "+v"(br20), "+v"(br21), "+v"(br22), "+v"(br23),
                              "+v"(bz20), "+v"(bz21), "+v"(bz22), "+v"(bz23),
                              "+v"(bn20), "+v"(bn21), "+v"(bn22), "+v"(bn23));
            // A-fragments: SHARED by both col-tiles (the halved-LDS lever)
            const int ab = cl * 136 + gq * 8;
            half8 a0 = *(const half8*)&H_half[ab];
            half8 a1 = *(const half8*)&H_half[ab + 32];
            half8 a2 = *(const half8*)&H_half[ab + 64];
            half8 a3 = *(const half8*)&H_half[ab + 96];
            float g1 = gam4[t * 4 + gq];
            float q1 = r4[t * 4 + gq];

            f32x4 z4 = {0.f, 0.f, 0.f, 0.f};
            f32x4 accr1 = z4, accz1 = z4, accn1 = z4;
            f32x4 accr2 = z4, accz2 = z4, accn2 = z4;
            accr1[0] = fmaf(g1, gr_pd1, fmaf(q1, gr_pr1, gr_b1));
            accz1[0] = fmaf(g1, gz_pd1, fmaf(q1, gz_pr1, gz_b1));
            accn1[0] = gn_bh1;
            float gin1 = fmaf(g1, gn_pd1, fmaf(q1, gn_pr1, gn_b1));
            accr2[0] = fmaf(g1, gr_pd2, fmaf(q1, gr_pr2, gr_b2));
            accz2[0] = fmaf(g1, gz_pd2, fmaf(q1, gz_pr2, gz_b2));
            accn2[0] = gn_bh2;
            float gin2 = fmaf(g1, gn_pd2, fmaf(q1, gn_pr2, gn_b2));

            // tile 1 (12 MFMA)
            accr1 = __builtin_amdgcn_mfma_f32_16x16x32_f16(a0, br10, accr1, 0, 0, 0);
            accr1 = __builtin_amdgcn_mfma_f32_16x16x32_f16(a1, br11, accr1, 0, 0, 0);
            accr1 = __builtin_amdgcn_mfma_f32_16x16x32_f16(a2, br12, accr1, 0, 0, 0);
            accr1 = __builtin_amdgcn_mfma_f32_16x16x32_f16(a3, br13, accr1, 0, 0, 0);
            accz1 = __builtin_amdgcn_mfma_f32_16x16x32_f16(a0, bz10, accz1, 0, 0, 0);
            accz1 = __builtin_amdgcn_mfma_f32_16x16x32_f16(a1, bz11, accz1, 0, 0, 0);
            accz1 = __builtin_amdgcn_mfma_f32_16x16x32_f16(a2, bz12, accz1, 0, 0, 0);
            accz1 = __builtin_amdgcn_mfma_f32_16x16x32_f16(a3, bz13, accz1, 0, 0, 0);
            accn1 = __builtin_amdgcn_mfma_f32_16x16x32_f16(a0, bn10, accn1, 0, 0, 0);
            accn1 = __builtin_amdgcn_mfma_f32_16x16x32_f16(a1, bn11, accn1, 0, 0, 0);
            accn1 = __builtin_amdgcn_mfma_f32_16x16x32_f16(a2, bn12, accn1, 0, 0, 0);
            accn1 = __builtin_amdgcn_mfma_f32_16x16x32_f16(a3, bn13, accn1, 0, 0, 0);
            // tile 2 (12 MFMA; overlaps tile-1 gates on the other pipes)
            accr2 = __builtin_amdgcn_mfma_f32_16x16x32_f16(a0, br20, accr2, 0, 0, 0);
            accr2 = __builtin_amdgcn_mfma_f32_16x16x32_f16(a1, br21, accr2, 0, 0, 0);
            accr2 = __builtin_amdgcn_mfma_f32_16x16x32_f16(a2, br22, accr2, 0, 0, 0);
            accr2 = __builtin_amdgcn_mfma_f32_16x16x32_f16(a3, br23, accr2, 0, 0, 0);
            accz2 = __builtin_amdgcn_mfma_f32_16x16x32_f16(a0, bz20, accz2, 0, 0, 0);
            accz2 = __builtin_amdgcn_mfma_f32_16x16x32_f16(a1, bz21, accz2, 0, 0, 0);
            accz2 = __builtin_amdgcn_mfma_f32_16x16x32_f16(a2, bz22, accz2, 0, 0, 0);
            accz2 = __builtin_amdgcn_mfma_f32_16x16x32_f16(a3, bz23, accz2, 0, 0, 0);
            accn2 = __builtin_amdgcn_mfma_f32_16x16x32_f16(a0, bn20, accn2, 0, 0, 0);
            accn2 = __builtin_amdgcn_mfma_f32_16x16x32_f16(a1, bn21, accn2, 0, 0, 0);
            accn2 = __builtin_amdgcn_mfma_f32_16x16x32_f16(a2, bn22, accn2, 0, 0, 0);
            accn2 = __builtin_amdgcn_mfma_f32_16x16x32_f16(a3, bn23, accn2, 0, 0, 0);

            // gates for both cols (elem 0 = batch row b0+gq)
            {
                float rg1 = sigm(accr1[0]);
                float zg1 = sigm(accz1[0]);
                float ng1 = tanh_f(fmaf(rg1, accn1[0], gin1));
                h1 = fmaf(1.f - zg1, ng1, zg1 * h1);
                float rg2 = sigm(accr2[0]);
                float zg2 = sigm(accz2[0]);
                float ng2 = tanh_f(fmaf(rg2, accn2[0], gin2));
                h2 = fmaf(1.f - zg2, ng2, zg2 * h2);
                H_half[(gq * 4) * 136 + c1] = (_Float16)h1;
                H_half[(gq * 4) * 136 + c2] = (_Float16)h2;
                hp[t * VV + c1] = h1;
                hp[t * VV + c2] = h2;
            }
            soft_barrier();   // LDS H_half visibility; h_out stays in flight
        }
    } else {
        // ================= memory-scan path: 2 phases (256 thr) ============
        int b = blockIdx.x - NGRU;
        const float* uc = ws + 768;
        const float* ud = ws + 896;
        const float* ur = ws + 1024;
        for (int i = tid; i < KN; i += 256) C[i] = 0.f;
        if (tid < TT) {
            gam_row[tid] = D_emb[d_seq[b * TT + tid]];
            r_row[tid] = r_seq[b * TT + tid];
            c_row[tid] = c_seq[b * TT + tid];
        }
        if (tid == 0) c_row[TT] = 0;
        __syncthreads();

        // ---- phase 1: wave0 scans; C[c(t+1)] prefetch + select ----
        if (tid < 64) {
            int l = tid;
            float uc0 = uc[l], uc1 = uc[l + 64];
            float ud0 = ud[l], ud1 = ud[l + 64];
            float ur0 = ur[l], ur1 = ur[l + 64];
            float ba0 = b2a[l], ba1 = b2a[l + 64];
            float wb0 = W2b[l], wb1 = W2b[l + 64];
            float bb = b2b[0];
            float beta = 0.f;
            int ct = c_row[0];
            for (int t = 0; t < TT; ++t) {
                int ct1 = c_row[t + 1];
                float cpref = C[ct1];
                float g = gam_row[t], rr = r_row[t];
                float hh0 = fmaxf(fmaf(beta, uc0, fmaf(g, ud0, fmaf(rr, ur0, ba0))), 0.f);
                float hh1 = fmaxf(fmaf(beta, uc1, fmaf(g, ud1, fmaf(rr, ur1, ba1))), 0.f);
                float p = fmaf(hh0, wb0, hh1 * wb1);
                #pragma unroll
                for (int m = 32; m > 0; m >>= 1) p += __shfl_xor(p, m);
                float nc = p + bb;
                if (l == 0) { C[ct] = nc; n_row[t] = nc; }
                beta = (ct1 == ct) ? nc : cpref;
                ct = ct1;
            }
        }
        __syncthreads();

        // ---- phase 2: 250 threads reconstruct C_out (8 floats/lane) ----
        int k0 = tid * 8;
        if (k0 < KN) {
            float4 cur0 = {0.f, 0.f, 0.f, 0.f};
            float4 cur1 = {0.f, 0.f, 0.f, 0.f};
            float* cop = C_out + (size_t)b * TT * KN + k0;
            for (int t = 0; t < TT; ++t) {
                int c = c_row[t];
                unsigned d = (unsigned)(c - k0);
                if (d < 8u) {
                    float v = n_row[t];
                    cur0.x = (d == 0u) ? v : cur0.x;
                    cur0.y = (d == 1u) ? v : cur0.y;
                    cur0.z = (d == 2u) ? v : cur0.z;
                    cur0.w = (d == 3u) ? v : cur0.w;
                    cur1.x = (d == 4u) ? v : cur1.x;
                    cur1.y = (d == 5u) ? v : cur1.y;
                    cur1.z = (d == 6u) ? v : cur1.z;
                    cur1.w = (d == 7u) ? v : cur1.w;
                }
                *(float4*)(cop + (size_t)t * KN) = cur0;
                *(float4*)(cop + (size_t)t * KN + 4) = cur1;
            }
        }
    }
}

// ---------------- alpha head: W1a staged in LDS (padded), bf16 MFMA ----------
__device__ __forceinline__ short f2bf(float f) {
    uint32_t u = __float_as_uint(f);
    u = (u + 0x7FFFu + ((u >> 16) & 1u)) >> 16;
    return (short)u;
}
__device__ __forceinline__ bf16x8 load_cvt8(const float* p) {
    float4 a = *(const float4*)p;
    float4 c = *(const float4*)(p + 4);
    bf16x8 r;
    r[0] = f2bf(a.x); r[1] = f2bf(a.y); r[2] = f2bf(a.z); r[3] = f2bf(a.w);
    r[4] = f2bf(c.x); r[5] = f2bf(c.y); r[6] = f2bf(c.z); r[7] = f2bf(c.w);
    return r;
}

__global__ __launch_bounds__(512) void alpha_kernel(
    const float* __restrict__ h_seq, const float* __restrict__ W1a,
    const float* __restrict__ b1a, const float* __restrict__ W1b,
    const float* __restrict__ b1b, float* __restrict__ alpha)
{
    __shared__ __align__(16) short W1s[128 * 136];   // bf16, padded stride 136
    __shared__ float b1s[128], w1bs[128];
    int tid = threadIdx.x;
    for (int i = tid * 8; i < 128 * 128; i += 512 * 8) {
        int row = i >> 7, col = i & 127;
        *(bf16x8*)&W1s[row * 136 + col] = load_cvt8(W1a + i);
    }
    if (tid < 128) { b1s[tid] = b1a[tid]; w1bs[tid] = W1b[tid]; }
    __syncthreads();

    int wave = tid >> 6, lane = tid & 63;
    int tile = blockIdx.x * 8 + wave;      // 800 tiles of 16 rows, 100 blocks
    int rowbase = tile * 16;
    int rl = lane & 15, g = lane >> 4;
    const float* hp = h_seq + (size_t)(rowbase + rl) * VV + g * 8;
    bf16x8 a0 = load_cvt8(hp);
    bf16x8 a1 = load_cvt8(hp + 32);
    bf16x8 a2 = load_cvt8(hp + 64);
    bf16x8 a3 = load_cvt8(hp + 96);
    float p0 = 0.f, p1 = 0.f, p2 = 0.f, p3 = 0.f;
    float bb = b1b[0];
    #pragma unroll
    for (int jt = 0; jt < 8; ++jt) {
        int j = jt * 16 + rl;
        const short* wp = &W1s[j * 136 + g * 8];
        f32x4 acc = {0.f, 0.f, 0.f, 0.f};
        acc = __builtin_amdgcn_mfma_f32_16x16x32_bf16(a0, *(const bf16x8*)wp, acc, 0, 0, 0);
        acc = __builtin_amdgcn_mfma_f32_16x16x32_bf16(a1, *(const bf16x8*)(wp + 32), acc, 0, 0, 0);
        acc = __builtin_amdgcn_mfma_f32_16x16x32_bf16(a2, *(const bf16x8*)(wp + 64), acc, 0, 0, 0);
        acc = __builtin_amdgcn_mfma_f32_16x16x32_bf16(a3, *(const bf16x8*)(wp + 96), acc, 0, 0, 0);
        float bj = b1s[j], wj = w1bs[j];
        p0 += fmaxf(acc[0] + bj, 0.f) * wj;
        p1 += fmaxf(acc[1] + bj, 0.f) * wj;
        p2 += fmaxf(acc[2] + bj, 0.f) * wj;
        p3 += fmaxf(acc[3] + bj, 0.f) * wj;
    }
    #pragma unroll
    for (int m = 1; m < 16; m <<= 1) {
        p0 += __shfl_xor(p0, m);
        p1 += __shfl_xor(p1, m);
        p2 += __shfl_xor(p2, m);
        p3 += __shfl_xor(p3, m);
    }
    if (rl == 0) {
        alpha[rowbase + g * 4 + 0] = p0 + bb;
        alpha[rowbase + g * 4 + 1] = p1 + bb;
        alpha[rowbase + g * 4 + 2] = p2 + bb;
        alpha[rowbase + g * 4 + 3] = p3 + bb;
    }
}

extern "C" void kernel_launch(void* const* d_in, const int* in_sizes, int n_in,
                              void* d_out, int out_size, void* d_ws, size_t ws_size,
                              hipStream_t stream)
{
    const int*   c_seq = (const int*)d_in[0];
    const int*   d_seq = (const int*)d_in[1];
    const float* r_seq = (const float*)d_in[2];
    const float* D_emb = (const float*)d_in[3];
    const float* v_d   = (const float*)d_in[4];
    const float* v_r   = (const float*)d_in[5];
    const float* v_c   = (const float*)d_in[6];
    const float* W_ih  = (const float*)d_in[7];
    const float* W_hh  = (const float*)d_in[8];
    const float* b_ih  = (const float*)d_in[9];
    const float* b_hh  = (const float*)d_in[10];
    const float* W1a   = (const float*)d_in[11];
    const float* b1a   = (const float*)d_in[12];
    const float* W1b   = (const float*)d_in[13];
    const float* b1b   = (const float*)d_in[14];
    const float* W2a   = (const float*)d_in[15];
    const float* b2a   = (const float*)d_in[16];
    const float* W2b   = (const float*)d_in[17];
    const float* b2b   = (const float*)d_in[18];

    float* out   = (float*)d_out;
    float* alpha = out;                       // 12800
    float* h_seq = out + 12800;               // 1,638,400
    float* C_out = out + 12800 + 1638400;     // 25,600,000
    float* ws    = (float*)d_ws;

    hipLaunchKernelGGL(pre_kernel, dim3(2), dim3(256), 0, stream,
                       v_d, v_r, v_c, W_ih, W2a, ws);
    hipLaunchKernelGGL(fused_kernel, dim3(NGRU + BB), dim3(256), 0, stream,
                       c_seq, d_seq, r_seq, D_emb, W_hh, b_ih, b_hh,
                       W2b, b2a, b2b, ws, C_out, h_seq);
    hipLaunchKernelGGL(alpha_kernel, dim3(100), dim3(512), 0, stream,
                       h_seq, W1a, b1a, W1b, b1b, alpha);
}

// Round 23
// 124.340 us; speedup vs baseline: 1.0975x; 1.0975x over previous
//
#include <hip/hip_runtime.h>
#include <hip/hip_bf16.h>
#include <cstdint>

#define BB 64
#define TT 200
#define KN 2000
#define VV 128
#define NGRU 16   // GRU blocks; each handles 4 batch rows + its 50 alpha tiles

typedef __attribute__((ext_vector_type(8))) short bf16x8;
typedef __attribute__((ext_vector_type(4))) float f32x4;
typedef _Float16 half8 __attribute__((ext_vector_type(8)));

// ws layout (floats): pd[384]@0, pr[384]@384, uc[128]@768, ud[128]@896, ur[128]@1024

// r11/r13: IEEE divides were the gate chain; rcp forms (~1ulp) are fine.
__device__ __forceinline__ float sigm(float x) {
    return __builtin_amdgcn_rcpf(1.f + __expf(-x));
}
__device__ __forceinline__ float tanh_f(float x) {
    float e = __expf(2.f * x);
    return 1.f - 2.f * __builtin_amdgcn_rcpf(e + 1.f);
}

// r17: spin barriers lose 3x to s_barrier. r20-r22: scan structure r19 is the
// local optimum (wave count / per-wave work / chain depth / LDS all isolated).
__device__ __forceinline__ void soft_barrier() {
    asm volatile("s_waitcnt lgkmcnt(0)" ::: "memory");
    __builtin_amdgcn_s_barrier();
    __builtin_amdgcn_sched_barrier(0);
}

// ---------------- precompute: small projection vectors (once, chip-wide) -----
__global__ void pre_kernel(const float* __restrict__ v_d, const float* __restrict__ v_r,
                           const float* __restrict__ v_c, const float* __restrict__ W_ih,
                           const float* __restrict__ W2a, float* __restrict__ ws)
{
    int g = blockIdx.x * 256 + threadIdx.x;   // grid 2 x 256 = 512 threads
    float* pd = ws;
    float* pr = ws + 384;
    float* uc = ws + 768;
    float* ud = ws + 896;
    float* ur = ws + 1024;
    if (g < 384) {
        float a = 0.f, b = 0.f;
        for (int k = 0; k < VV; ++k) {
            a = fmaf(W_ih[g * 256 + k], v_d[k], a);
            b = fmaf(W_ih[g * 256 + VV + k], v_r[k], b);
        }
        pd[g] = a; pr[g] = b;
    }
    if (g < VV) {
        float a = 0.f, b = 0.f, c = 0.f;
        for (int k = 0; k < VV; ++k) {
            a = fmaf(W2a[g * 384 + k], v_c[k], a);
            b = fmaf(W2a[g * 384 + VV + k], v_d[k], b);
            c = fmaf(W2a[g * 384 + 2 * VV + k], v_r[k], c);
        }
        uc[g] = a; ud[g] = b; ur[g] = c;
    }
}

__device__ __forceinline__ half8 load_cvt8h(const float* p) {
    float4 a = *(const float4*)p;
    float4 c = *(const float4*)(p + 4);
    half8 r;
    r[0] = (_Float16)a.x; r[1] = (_Float16)a.y; r[2] = (_Float16)a.z; r[3] = (_Float16)a.w;
    r[4] = (_Float16)c.x; r[5] = (_Float16)c.y; r[6] = (_Float16)c.z; r[7] = (_Float16)c.w;
    return r;
}

__device__ __forceinline__ short f2bf(float f) {
    uint32_t u = __float_as_uint(f);
    u = (u + 0x7FFFu + ((u >> 16) & 1u)) >> 16;
    return (short)u;
}
__device__ __forceinline__ bf16x8 load_cvt8(const float* p) {
    float4 a = *(const float4*)p;
    float4 c = *(const float4*)(p + 4);
    bf16x8 r;
    r[0] = f2bf(a.x); r[1] = f2bf(a.y); r[2] = f2bf(a.z); r[3] = f2bf(a.w);
    r[4] = f2bf(c.x); r[5] = f2bf(c.y); r[6] = f2bf(c.z); r[7] = f2bf(c.w);
    return r;
}

// ---------------- fused: blocks 0-15 GRU scan + alpha tiles, 16-79 mem scan --
// Scan = exact r19 structure (85.6us proven). After the scan each GRU block
// computes alpha for its own 800 flattened rows (50 tiles) from LDS-staged
// W1a -- removes the separate alpha dispatch + gap (~12us tail).
__global__ __launch_bounds__(512, 1) void fused_kernel(
    const int* __restrict__ c_seq, const int* __restrict__ d_seq,
    const float* __restrict__ r_seq, const float* __restrict__ D_emb,
    const float* __restrict__ Whh, const float* __restrict__ bih,
    const float* __restrict__ bhh, const float* __restrict__ W2b,
    const float* __restrict__ b2a, const float* __restrict__ b2b,
    const float* __restrict__ W1a, const float* __restrict__ b1a,
    const float* __restrict__ W1b, const float* __restrict__ b1b,
    const float* __restrict__ ws, float* __restrict__ C_out,
    float* __restrict__ h_out, float* __restrict__ alpha)
{
    __shared__ __align__(16) _Float16 H_half[16 * 136];   // rows ≢0 mod 4 stay 0
    __shared__ __align__(8) float gam4[TT * 4], r4[TT * 4];  // [t][rr]
    __shared__ __align__(16) float C[KN];
    __shared__ float gam_row[TT], r_row[TT], n_row[TT];
    __shared__ int c_row[TT + 1];
    __shared__ __align__(16) short W1s[128 * 136];   // bf16 W1a, padded stride 136
    __shared__ float b1s[128], w1bs[128];

    int tid = threadIdx.x;

    if (blockIdx.x < NGRU) {
        // ================= GRU path: 4 batch rows =================
        int b0 = blockIdx.x * 4;
        const float* pd = ws;
        const float* pr = ws + 384;

        for (int i = tid; i < TT * 4; i += 512) {
            int t = i >> 2, rr = i & 3;
            gam4[i] = D_emb[d_seq[(b0 + rr) * TT + t]];
            r4[i] = r_seq[(b0 + rr) * TT + t];
        }
        for (int i = tid; i < 16 * 136; i += 512) H_half[i] = (_Float16)0.f;
        // stage W1a (bf16, padded) + alpha biases for the post-scan head
        for (int i = tid * 8; i < 128 * 128; i += 512 * 8) {
            int row = i >> 7, col = i & 127;
            *(bf16x8*)&W1s[row * 136 + col] = load_cvt8(W1a + i);
        }
        if (tid < 128) { b1s[tid] = b1a[tid]; w1bs[tid] = W1b[tid]; }

        int wid = tid >> 6, l = tid & 63;
        int cl = l & 15, gq = l >> 4;
        int nn = wid * 16 + cl;      // output col (0..127)
        // batch row this lane owns: b0+gq, at MFMA row gq*4 (acc[0]).

        // B-fragments: 12 frags = 48 regs, resident (r9: FETCH 590KB confirmed)
        const float* wr = Whh + (size_t)nn * VV + gq * 8;
        const float* wz = Whh + (size_t)(nn + 128) * VV + gq * 8;
        const float* wn = Whh + (size_t)(nn + 256) * VV + gq * 8;
        half8 br0 = load_cvt8h(wr),      br1 = load_cvt8h(wr + 32),
              br2 = load_cvt8h(wr + 64), br3 = load_cvt8h(wr + 96);
        half8 bz0 = load_cvt8h(wz),      bz1 = load_cvt8h(wz + 32),
              bz2 = load_cvt8h(wz + 64), bz3 = load_cvt8h(wz + 96);
        half8 bn0 = load_cvt8h(wn),      bn1 = load_cvt8h(wn + 32),
              bn2 = load_cvt8h(wn + 64), bn3 = load_cvt8h(wn + 96);

        // per-lane gi fold scalars from ws (col nn fixed per lane)
        float gr_pd = pd[nn],        gr_pr = pr[nn],        gr_b = bih[nn] + bhh[nn];
        float gz_pd = pd[nn + 128],  gz_pr = pr[nn + 128],  gz_b = bih[nn + 128] + bhh[nn + 128];
        float gn_pd = pd[nn + 256],  gn_pr = pr[nn + 256],  gn_b = bih[nn + 256];
        float gn_bh = bhh[nn + 256];

        float h0 = 0.f;
        __syncthreads();   // setup barrier

        for (int t = 0; t < TT; ++t) {
            asm volatile("" : "+v"(br0), "+v"(br1), "+v"(br2), "+v"(br3),
                              "+v"(bz0), "+v"(bz1), "+v"(bz2), "+v"(bz3),
                              "+v"(bn0), "+v"(bn1), "+v"(bn2), "+v"(bn3));
            // A-fragments + per-step scalars (fold overlaps ds_read latency)
            const int ab = cl * 136 + gq * 8;
            half8 a0 = *(const half8*)&H_half[ab];
            half8 a1 = *(const half8*)&H_half[ab + 32];
            half8 a2 = *(const half8*)&H_half[ab + 64];
            half8 a3 = *(const half8*)&H_half[ab + 96];
            float g1 = gam4[t * 4 + gq];
            float q1 = r4[t * 4 + gq];

            // gi fold as MFMA C-in (only acc[0] meaningful)
            f32x4 accr = {0.f, 0.f, 0.f, 0.f};
            f32x4 accz = {0.f, 0.f, 0.f, 0.f};
            f32x4 accn = {0.f, 0.f, 0.f, 0.f};
            accr[0] = fmaf(g1, gr_pd, fmaf(q1, gr_pr, gr_b));
            accz[0] = fmaf(g1, gz_pd, fmaf(q1, gz_pr, gz_b));
            accn[0] = gn_bh;
            float gin0 = fmaf(g1, gn_pd, fmaf(q1, gn_pr, gn_b));

            accr = __builtin_amdgcn_mfma_f32_16x16x32_f16(a0, br0, accr, 0, 0, 0);
            accr = __builtin_amdgcn_mfma_f32_16x16x32_f16(a1, br1, accr, 0, 0, 0);
            accr = __builtin_amdgcn_mfma_f32_16x16x32_f16(a2, br2, accr, 0, 0, 0);
            accr = __builtin_amdgcn_mfma_f32_16x16x32_f16(a3, br3, accr, 0, 0, 0);
            accz = __builtin_amdgcn_mfma_f32_16x16x32_f16(a0, bz0, accz, 0, 0, 0);
            accz = __builtin_amdgcn_mfma_f32_16x16x32_f16(a1, bz1, accz, 0, 0, 0);
            accz = __builtin_amdgcn_mfma_f32_16x16x32_f16(a2, bz2, accz, 0, 0, 0);
            accz = __builtin_amdgcn_mfma_f32_16x16x32_f16(a3, bz3, accz, 0, 0, 0);
            accn = __builtin_amdgcn_mfma_f32_16x16x32_f16(a0, bn0, accn, 0, 0, 0);
            accn = __builtin_amdgcn_mfma_f32_16x16x32_f16(a1, bn1, accn, 0, 0, 0);
            accn = __builtin_amdgcn_mfma_f32_16x16x32_f16(a2, bn2, accn, 0, 0, 0);
            accn = __builtin_amdgcn_mfma_f32_16x16x32_f16(a3, bn3, accn, 0, 0, 0);

            // gate: acc[0] = (batch row b0+gq, col nn), lane-local
            {
                float rg0 = sigm(accr[0]);
                float zg0 = sigm(accz[0]);
                float ng0 = tanh_f(fmaf(rg0, accn[0], gin0));
                h0 = fmaf(1.f - zg0, ng0, zg0 * h0);
                H_half[(gq * 4) * 136 + nn] = (_Float16)h0;
                h_out[((size_t)(b0 + gq) * TT + t) * VV + nn] = h0;
            }
            soft_barrier();   // LDS H_half visibility; h_out stays in flight
        }

        // ---------------- alpha head for this block's 50 tiles ----------------
        asm volatile("s_waitcnt vmcnt(0)" ::: "memory");  // own h stores done
        __syncthreads();                                  // all waves' stores done
        {
            int lane = l;
            int rl = lane & 15, g = lane >> 4;
            float bb = b1b[0];
            int rbase = b0 * TT;    // flattened row base (800 rows, 50 tiles)
            for (int tt = wid; tt < 50; tt += 8) {
                int rowbase = rbase + tt * 16;
                const float* hp = h_out + (size_t)(rowbase + rl) * VV + g * 8;
                bf16x8 a0 = load_cvt8(hp);
                bf16x8 a1 = load_cvt8(hp + 32);
                bf16x8 a2 = load_cvt8(hp + 64);
                bf16x8 a3 = load_cvt8(hp + 96);
                float p0 = 0.f, p1 = 0.f, p2 = 0.f, p3 = 0.f;
                #pragma unroll
                for (int jt = 0; jt < 8; ++jt) {
                    int j = jt * 16 + rl;
                    const short* wp = &W1s[j * 136 + g * 8];
                    f32x4 acc = {0.f, 0.f, 0.f, 0.f};
                    acc = __builtin_amdgcn_mfma_f32_16x16x32_bf16(a0, *(const bf16x8*)wp, acc, 0, 0, 0);
                    acc = __builtin_amdgcn_mfma_f32_16x16x32_bf16(a1, *(const bf16x8*)(wp + 32), acc, 0, 0, 0);
                    acc = __builtin_amdgcn_mfma_f32_16x16x32_bf16(a2, *(const bf16x8*)(wp + 64), acc, 0, 0, 0);
                    acc = __builtin_amdgcn_mfma_f32_16x16x32_bf16(a3, *(const bf16x8*)(wp + 96), acc, 0, 0, 0);
                    float bj = b1s[j], wj = w1bs[j];
                    p0 += fmaxf(acc[0] + bj, 0.f) * wj;
                    p1 += fmaxf(acc[1] + bj, 0.f) * wj;
                    p2 += fmaxf(acc[2] + bj, 0.f) * wj;
                    p3 += fmaxf(acc[3] + bj, 0.f) * wj;
                }
                #pragma unroll
                for (int m = 1; m < 16; m <<= 1) {
                    p0 += __shfl_xor(p0, m);
                    p1 += __shfl_xor(p1, m);
                    p2 += __shfl_xor(p2, m);
                    p3 += __shfl_xor(p3, m);
                }
                if (rl == 0) {
                    alpha[rowbase + g * 4 + 0] = p0 + bb;
                    alpha[rowbase + g * 4 + 1] = p1 + bb;
                    alpha[rowbase + g * 4 + 2] = p2 + bb;
                    alpha[rowbase + g * 4 + 3] = p3 + bb;
                }
            }
        }
    } else {
        // ================= memory-scan path: 2 phases =================
        int b = blockIdx.x - NGRU;
        const float* uc = ws + 768;
        const float* ud = ws + 896;
        const float* ur = ws + 1024;
        for (int i = tid; i < KN; i += 512) C[i] = 0.f;
        if (tid < TT) {
            gam_row[tid] = D_emb[d_seq[b * TT + tid]];
            r_row[tid] = r_seq[b * TT + tid];
            c_row[tid] = c_seq[b * TT + tid];
        }
        if (tid == 0) c_row[TT] = 0;
        __syncthreads();

        // ---- phase 1: wave0 scans; C[c(t+1)] prefetch + select ----
        if (tid < 64) {
            int l = tid;
            float uc0 = uc[l], uc1 = uc[l + 64];
            float ud0 = ud[l], ud1 = ud[l + 64];
            float ur0 = ur[l], ur1 = ur[l + 64];
            float ba0 = b2a[l], ba1 = b2a[l + 64];
            float wb0 = W2b[l], wb1 = W2b[l + 64];
            float bb = b2b[0];
            float beta = 0.f;
            int ct = c_row[0];
            for (int t = 0; t < TT; ++t) {
                int ct1 = c_row[t + 1];
                float cpref = C[ct1];
                float g = gam_row[t], rr = r_row[t];
                float hh0 = fmaxf(fmaf(beta, uc0, fmaf(g, ud0, fmaf(rr, ur0, ba0))), 0.f);
                float hh1 = fmaxf(fmaf(beta, uc1, fmaf(g, ud1, fmaf(rr, ur1, ba1))), 0.f);
                float p = fmaf(hh0, wb0, hh1 * wb1);
                #pragma unroll
                for (int m = 32; m > 0; m >>= 1) p += __shfl_xor(p, m);
                float nc = p + bb;
                if (l == 0) { C[ct] = nc; n_row[t] = nc; }
                beta = (ct1 == ct) ? nc : cpref;
                ct = ct1;
            }
        }
        __syncthreads();

        // ---- phase 2: all 8 waves reconstruct C_out (float4/lane) ----
        int k0 = tid * 4;
        if (k0 < KN) {
            float4 cur = {0.f, 0.f, 0.f, 0.f};
            float* cop = C_out + (size_t)b * TT * KN + k0;
            for (int t = 0; t < TT; ++t) {
                int c = c_row[t];
                unsigned d = (unsigned)(c - k0);
                if (d < 4u) {
                    float v = n_row[t];
                    cur.x = (d == 0u) ? v : cur.x;
                    cur.y = (d == 1u) ? v : cur.y;
                    cur.z = (d == 2u) ? v : cur.z;
                    cur.w = (d == 3u) ? v : cur.w;
                }
                *(float4*)(cop + (size_t)t * KN) = cur;
            }
        }
    }
}

extern "C" void kernel_launch(void* const* d_in, const int* in_sizes, int n_in,
                              void* d_out, int out_size, void* d_ws, size_t ws_size,
                              hipStream_t stream)
{
    const int*   c_seq = (const int*)d_in[0];
    const int*   d_seq = (const int*)d_in[1];
    const float* r_seq = (const float*)d_in[2];
    const float* D_emb = (const float*)d_in[3];
    const float* v_d   = (const float*)d_in[4];
    const float* v_r   = (const float*)d_in[5];
    const float* v_c   = (const float*)d_in[6];
    const float* W_ih  = (const float*)d_in[7];
    const float* W_hh  = (const float*)d_in[8];
    const float* b_ih  = (const float*)d_in[9];
    const float* b_hh  = (const float*)d_in[10];
    const float* W1a   = (const float*)d_in[11];
    const float* b1a   = (const float*)d_in[12];
    const float* W1b   = (const float*)d_in[13];
    const float* b1b   = (const float*)d_in[14];
    const float* W2a   = (const float*)d_in[15];
    const float* b2a   = (const float*)d_in[16];
    const float* W2b   = (const float*)d_in[17];
    const float* b2b   = (const float*)d_in[18];

    float* out   = (float*)d_out;
    float* alpha = out;                       // 12800
    float* h_seq = out + 12800;               // 1,638,400
    float* C_out = out + 12800 + 1638400;     // 25,600,000
    float* ws    = (float*)d_ws;

    hipLaunchKernelGGL(pre_kernel, dim3(2), dim3(256), 0, stream,
                       v_d, v_r, v_c, W_ih, W2a, ws);
    hipLaunchKernelGGL(fused_kernel, dim3(NGRU + BB), dim3(512), 0, stream,
                       c_seq, d_seq, r_seq, D_emb, W_hh, b_ih, b_hh,
                       W2b, b2a, b2b, W1a, b1a, W1b, b1b, ws, C_out,
                       h_seq, alpha);
}

// Round 24
// 116.756 us; speedup vs baseline: 1.1688x; 1.0650x over previous
//
#include <hip/hip_runtime.h>
#include <hip/hip_bf16.h>
#include <cstdint>

#define BB 64
#define TT 200
#define KN 2000
#define VV 128
#define NGRU 16   // GRU blocks; each handles 4 batch rows

typedef __attribute__((ext_vector_type(8))) short bf16x8;
typedef __attribute__((ext_vector_type(4))) float f32x4;
typedef _Float16 half8 __attribute__((ext_vector_type(8)));

// ws layout (floats): pd[384]@0, pr[384]@384, uc[128]@768, ud[128]@896, ur[128]@1024
// r18: projections must stay in the tiny pre_kernel (per-block dot128 = +41us).
// r23: alpha must stay a separate 100-block dispatch (fusing into 16 GRU
// blocks = +18us of L2-latency-exposed re-reads vs -12us dispatch saving).

// r11/r13: IEEE divides were the gate chain; rcp forms (~1ulp) are fine.
__device__ __forceinline__ float sigm(float x) {
    return __builtin_amdgcn_rcpf(1.f + __expf(-x));
}
__device__ __forceinline__ float tanh_f(float x) {
    float e = __expf(2.f * x);
    return 1.f - 2.f * __builtin_amdgcn_rcpf(e + 1.f);
}

// r17: LDS spin barriers lose 3x to s_barrier. r20-r22: r19 scan structure is
// the local optimum (wave count / per-wave work / chain depth / LDS isolated).
__device__ __forceinline__ void soft_barrier() {
    asm volatile("s_waitcnt lgkmcnt(0)" ::: "memory");
    __builtin_amdgcn_s_barrier();
    __builtin_amdgcn_sched_barrier(0);
}

// ---------------- precompute: small projection vectors (once, chip-wide) -----
__global__ void pre_kernel(const float* __restrict__ v_d, const float* __restrict__ v_r,
                           const float* __restrict__ v_c, const float* __restrict__ W_ih,
                           const float* __restrict__ W2a, float* __restrict__ ws)
{
    int g = blockIdx.x * 256 + threadIdx.x;   // grid 2 x 256 = 512 threads
    float* pd = ws;
    float* pr = ws + 384;
    float* uc = ws + 768;
    float* ud = ws + 896;
    float* ur = ws + 1024;
    if (g < 384) {
        float a = 0.f, b = 0.f;
        for (int k = 0; k < VV; ++k) {
            a = fmaf(W_ih[g * 256 + k], v_d[k], a);
            b = fmaf(W_ih[g * 256 + VV + k], v_r[k], b);
        }
        pd[g] = a; pr[g] = b;
    }
    if (g < VV) {
        float a = 0.f, b = 0.f, c = 0.f;
        for (int k = 0; k < VV; ++k) {
            a = fmaf(W2a[g * 384 + k], v_c[k], a);
            b = fmaf(W2a[g * 384 + VV + k], v_d[k], b);
            c = fmaf(W2a[g * 384 + 2 * VV + k], v_r[k], c);
        }
        uc[g] = a; ud[g] = b; ur[g] = c;
    }
}

__device__ __forceinline__ half8 load_cvt8h(const float* p) {
    float4 a = *(const float4*)p;
    float4 c = *(const float4*)(p + 4);
    half8 r;
    r[0] = (_Float16)a.x; r[1] = (_Float16)a.y; r[2] = (_Float16)a.z; r[3] = (_Float16)a.w;
    r[4] = (_Float16)c.x; r[5] = (_Float16)c.y; r[6] = (_Float16)c.z; r[7] = (_Float16)c.w;
    return r;
}

// ---------------- fused: blocks 0-15 GRU (4 rows each, MFMA), 16-79 mem scan --
// r19 structure: 16 blocks x 4 batch rows at MFMA rows ≡0 mod 4, lane gq's
// acc[0] is the single valid row -> 1-row GATE. 85.6us proven.
__global__ __launch_bounds__(512, 1) void fused_kernel(
    const int* __restrict__ c_seq, const int* __restrict__ d_seq,
    const float* __restrict__ r_seq, const float* __restrict__ D_emb,
    const float* __restrict__ Whh, const float* __restrict__ bih,
    const float* __restrict__ bhh, const float* __restrict__ W2b,
    const float* __restrict__ b2a, const float* __restrict__ b2b,
    const float* __restrict__ ws, float* __restrict__ C_out,
    float* __restrict__ h_out)
{
    __shared__ __align__(16) _Float16 H_half[16 * 136];   // rows ≢0 mod 4 stay 0
    __shared__ __align__(8) float gam4[TT * 4], r4[TT * 4];  // [t][rr]
    __shared__ __align__(16) float C[KN];
    __shared__ float gam_row[TT], r_row[TT], n_row[TT];
    __shared__ int c_row[TT + 1];

    int tid = threadIdx.x;

    if (blockIdx.x < NGRU) {
        // ================= GRU path: 4 batch rows =================
        int b0 = blockIdx.x * 4;
        const float* pd = ws;
        const float* pr = ws + 384;

        for (int i = tid; i < TT * 4; i += 512) {
            int t = i >> 2, rr = i & 3;
            gam4[i] = D_emb[d_seq[(b0 + rr) * TT + t]];
            r4[i] = r_seq[(b0 + rr) * TT + t];
        }
        for (int i = tid; i < 16 * 136; i += 512) H_half[i] = (_Float16)0.f;

        int wid = tid >> 6, l = tid & 63;
        int cl = l & 15, gq = l >> 4;
        int nn = wid * 16 + cl;      // output col (0..127)
        // batch row this lane owns: b0+gq, at MFMA row gq*4 (acc[0]).

        // B-fragments: 12 frags = 48 regs, resident (r9: FETCH 590KB confirmed)
        const float* wr = Whh + (size_t)nn * VV + gq * 8;
        const float* wz = Whh + (size_t)(nn + 128) * VV + gq * 8;
        const float* wn = Whh + (size_t)(nn + 256) * VV + gq * 8;
        half8 br0 = load_cvt8h(wr),      br1 = load_cvt8h(wr + 32),
              br2 = load_cvt8h(wr + 64), br3 = load_cvt8h(wr + 96);
        half8 bz0 = load_cvt8h(wz),      bz1 = load_cvt8h(wz + 32),
              bz2 = load_cvt8h(wz + 64), bz3 = load_cvt8h(wz + 96);
        half8 bn0 = load_cvt8h(wn),      bn1 = load_cvt8h(wn + 32),
              bn2 = load_cvt8h(wn + 64), bn3 = load_cvt8h(wn + 96);

        // per-lane gi fold scalars from ws (col nn fixed per lane)
        float gr_pd = pd[nn],        gr_pr = pr[nn],        gr_b = bih[nn] + bhh[nn];
        float gz_pd = pd[nn + 128],  gz_pr = pr[nn + 128],  gz_b = bih[nn + 128] + bhh[nn + 128];
        float gn_pd = pd[nn + 256],  gn_pr = pr[nn + 256],  gn_b = bih[nn + 256];
        float gn_bh = bhh[nn + 256];

        float h0 = 0.f;
        __syncthreads();   // setup barrier

        for (int t = 0; t < TT; ++t) {
            asm volatile("" : "+v"(br0), "+v"(br1), "+v"(br2), "+v"(br3),
                              "+v"(bz0), "+v"(bz1), "+v"(bz2), "+v"(bz3),
                              "+v"(bn0), "+v"(bn1), "+v"(bn2), "+v"(bn3));
            // A-fragments + per-step scalars (fold overlaps ds_read latency)
            const int ab = cl * 136 + gq * 8;
            half8 a0 = *(const half8*)&H_half[ab];
            half8 a1 = *(const half8*)&H_half[ab + 32];
            half8 a2 = *(const half8*)&H_half[ab + 64];
            half8 a3 = *(const half8*)&H_half[ab + 96];
            float g1 = gam4[t * 4 + gq];
            float q1 = r4[t * 4 + gq];

            // gi fold as MFMA C-in (only acc[0] meaningful)
            f32x4 accr = {0.f, 0.f, 0.f, 0.f};
            f32x4 accz = {0.f, 0.f, 0.f, 0.f};
            f32x4 accn = {0.f, 0.f, 0.f, 0.f};
            accr[0] = fmaf(g1, gr_pd, fmaf(q1, gr_pr, gr_b));
            accz[0] = fmaf(g1, gz_pd, fmaf(q1, gz_pr, gz_b));
            accn[0] = gn_bh;
            float gin0 = fmaf(g1, gn_pd, fmaf(q1, gn_pr, gn_b));

            accr = __builtin_amdgcn_mfma_f32_16x16x32_f16(a0, br0, accr, 0, 0, 0);
            accr = __builtin_amdgcn_mfma_f32_16x16x32_f16(a1, br1, accr, 0, 0, 0);
            accr = __builtin_amdgcn_mfma_f32_16x16x32_f16(a2, br2, accr, 0, 0, 0);
            accr = __builtin_amdgcn_mfma_f32_16x16x32_f16(a3, br3, accr, 0, 0, 0);
            accz = __builtin_amdgcn_mfma_f32_16x16x32_f16(a0, bz0, accz, 0, 0, 0);
            accz = __builtin_amdgcn_mfma_f32_16x16x32_f16(a1, bz1, accz, 0, 0, 0);
            accz = __builtin_amdgcn_mfma_f32_16x16x32_f16(a2, bz2, accz, 0, 0, 0);
            accz = __builtin_amdgcn_mfma_f32_16x16x32_f16(a3, bz3, accz, 0, 0, 0);
            accn = __builtin_amdgcn_mfma_f32_16x16x32_f16(a0, bn0, accn, 0, 0, 0);
            accn = __builtin_amdgcn_mfma_f32_16x16x32_f16(a1, bn1, accn, 0, 0, 0);
            accn = __builtin_amdgcn_mfma_f32_16x16x32_f16(a2, bn2, accn, 0, 0, 0);
            accn = __builtin_amdgcn_mfma_f32_16x16x32_f16(a3, bn3, accn, 0, 0, 0);

            // gate: acc[0] = (batch row b0+gq, col nn), lane-local
            {
                float rg0 = sigm(accr[0]);
                float zg0 = sigm(accz[0]);
                float ng0 = tanh_f(fmaf(rg0, accn[0], gin0));
                h0 = fmaf(1.f - zg0, ng0, zg0 * h0);
                H_half[(gq * 4) * 136 + nn] = (_Float16)h0;
                h_out[((size_t)(b0 + gq) * TT + t) * VV + nn] = h0;
            }
            soft_barrier();   // LDS H_half visibility; h_out stays in flight
        }
    } else {
        // ================= memory-scan path: 2 phases =================
        int b = blockIdx.x - NGRU;
        const float* uc = ws + 768;
        const float* ud = ws + 896;
        const float* ur = ws + 1024;
        for (int i = tid; i < KN; i += 512) C[i] = 0.f;
        if (tid < TT) {
            gam_row[tid] = D_emb[d_seq[b * TT + tid]];
            r_row[tid] = r_seq[b * TT + tid];
            c_row[tid] = c_seq[b * TT + tid];
        }
        if (tid == 0) c_row[TT] = 0;
        __syncthreads();

        // ---- phase 1: wave0 scans; C[c(t+1)] prefetch + select ----
        if (tid < 64) {
            int l = tid;
            float uc0 = uc[l], uc1 = uc[l + 64];
            float ud0 = ud[l], ud1 = ud[l + 64];
            float ur0 = ur[l], ur1 = ur[l + 64];
            float ba0 = b2a[l], ba1 = b2a[l + 64];
            float wb0 = W2b[l], wb1 = W2b[l + 64];
            float bb = b2b[0];
            float beta = 0.f;
            int ct = c_row[0];
            for (int t = 0; t < TT; ++t) {
                int ct1 = c_row[t + 1];
                float cpref = C[ct1];
                float g = gam_row[t], rr = r_row[t];
                float hh0 = fmaxf(fmaf(beta, uc0, fmaf(g, ud0, fmaf(rr, ur0, ba0))), 0.f);
                float hh1 = fmaxf(fmaf(beta, uc1, fmaf(g, ud1, fmaf(rr, ur1, ba1))), 0.f);
                float p = fmaf(hh0, wb0, hh1 * wb1);
                #pragma unroll
                for (int m = 32; m > 0; m >>= 1) p += __shfl_xor(p, m);
                float nc = p + bb;
                if (l == 0) { C[ct] = nc; n_row[t] = nc; }
                beta = (ct1 == ct) ? nc : cpref;
                ct = ct1;
            }
        }
        __syncthreads();

        // ---- phase 2: all 8 waves reconstruct C_out (float4/lane) ----
        int k0 = tid * 4;
        if (k0 < KN) {
            float4 cur = {0.f, 0.f, 0.f, 0.f};
            float* cop = C_out + (size_t)b * TT * KN + k0;
            for (int t = 0; t < TT; ++t) {
                int c = c_row[t];
                unsigned d = (unsigned)(c - k0);
                if (d < 4u) {
                    float v = n_row[t];
                    cur.x = (d == 0u) ? v : cur.x;
                    cur.y = (d == 1u) ? v : cur.y;
                    cur.z = (d == 2u) ? v : cur.z;
                    cur.w = (d == 3u) ? v : cur.w;
                }
                *(float4*)(cop + (size_t)t * KN) = cur;
            }
        }
    }
}

// ---------------- alpha head: W1a staged in LDS (padded), bf16 MFMA ----------
__device__ __forceinline__ short f2bf(float f) {
    uint32_t u = __float_as_uint(f);
    u = (u + 0x7FFFu + ((u >> 16) & 1u)) >> 16;
    return (short)u;
}
__device__ __forceinline__ bf16x8 load_cvt8(const float* p) {
    float4 a = *(const float4*)p;
    float4 c = *(const float4*)(p + 4);
    bf16x8 r;
    r[0] = f2bf(a.x); r[1] = f2bf(a.y); r[2] = f2bf(a.z); r[3] = f2bf(a.w);
    r[4] = f2bf(c.x); r[5] = f2bf(c.y); r[6] = f2bf(c.z); r[7] = f2bf(c.w);
    return r;
}

__global__ __launch_bounds__(512) void alpha_kernel(
    const float* __restrict__ h_seq, const float* __restrict__ W1a,
    const float* __restrict__ b1a, const float* __restrict__ W1b,
    const float* __restrict__ b1b, float* __restrict__ alpha)
{
    __shared__ __align__(16) short W1s[128 * 136];   // bf16, padded stride 136
    __shared__ float b1s[128], w1bs[128];
    int tid = threadIdx.x;
    for (int i = tid * 8; i < 128 * 128; i += 512 * 8) {
        int row = i >> 7, col = i & 127;
        *(bf16x8*)&W1s[row * 136 + col] = load_cvt8(W1a + i);
    }
    if (tid < 128) { b1s[tid] = b1a[tid]; w1bs[tid] = W1b[tid]; }
    __syncthreads();

    int wave = tid >> 6, lane = tid & 63;
    int tile = blockIdx.x * 8 + wave;      // 800 tiles of 16 rows, 100 blocks
    int rowbase = tile * 16;
    int rl = lane & 15, g = lane >> 4;
    const float* hp = h_seq + (size_t)(rowbase + rl) * VV + g * 8;
    bf16x8 a0 = load_cvt8(hp);
    bf16x8 a1 = load_cvt8(hp + 32);
    bf16x8 a2 = load_cvt8(hp + 64);
    bf16x8 a3 = load_cvt8(hp + 96);
    float p0 = 0.f, p1 = 0.f, p2 = 0.f, p3 = 0.f;
    float bb = b1b[0];
    #pragma unroll
    for (int jt = 0; jt < 8; ++jt) {
        int j = jt * 16 + rl;
        const short* wp = &W1s[j * 136 + g * 8];
        f32x4 acc = {0.f, 0.f, 0.f, 0.f};
        acc = __builtin_amdgcn_mfma_f32_16x16x32_bf16(a0, *(const bf16x8*)wp, acc, 0, 0, 0);
        acc = __builtin_amdgcn_mfma_f32_16x16x32_bf16(a1, *(const bf16x8*)(wp + 32), acc, 0, 0, 0);
        acc = __builtin_amdgcn_mfma_f32_16x16x32_bf16(a2, *(const bf16x8*)(wp + 64), acc, 0, 0, 0);
        acc = __builtin_amdgcn_mfma_f32_16x16x32_bf16(a3, *(const bf16x8*)(wp + 96), acc, 0, 0, 0);
        float bj = b1s[j], wj = w1bs[j];
        p0 += fmaxf(acc[0] + bj, 0.f) * wj;
        p1 += fmaxf(acc[1] + bj, 0.f) * wj;
        p2 += fmaxf(acc[2] + bj, 0.f) * wj;
        p3 += fmaxf(acc[3] + bj, 0.f) * wj;
    }
    #pragma unroll
    for (int m = 1; m < 16; m <<= 1) {
        p0 += __shfl_xor(p0, m);
        p1 += __shfl_xor(p1, m);
        p2 += __shfl_xor(p2, m);
        p3 += __shfl_xor(p3, m);
    }
    if (rl == 0) {
        alpha[rowbase + g * 4 + 0] = p0 + bb;
        alpha[rowbase + g * 4 + 1] = p1 + bb;
        alpha[rowbase + g * 4 + 2] = p2 + bb;
        alpha[rowbase + g * 4 + 3] = p3 + bb;
    }
}

extern "C" void kernel_launch(void* const* d_in, const int* in_sizes, int n_in,
                              void* d_out, int out_size, void* d_ws, size_t ws_size,
                              hipStream_t stream)
{
    const int*   c_seq = (const int*)d_in[0];
    const int*   d_seq = (const int*)d_in[1];
    const float* r_seq = (const float*)d_in[2];
    const float* D_emb = (const float*)d_in[3];
    const float* v_d   = (const float*)d_in[4];
    const float* v_r   = (const float*)d_in[5];
    const float* v_c   = (const float*)d_in[6];
    const float* W_ih  = (const float*)d_in[7];
    const float* W_hh  = (const float*)d_in[8];
    const float* b_ih  = (const float*)d_in[9];
    const float* b_hh  = (const float*)d_in[10];
    const float* W1a   = (const float*)d_in[11];
    const float* b1a   = (const float*)d_in[12];
    const float* W1b   = (const float*)d_in[13];
    const float* b1b   = (const float*)d_in[14];
    const float* W2a   = (const float*)d_in[15];
    const float* b2a   = (const float*)d_in[16];
    const float* W2b   = (const float*)d_in[17];
    const float* b2b   = (const float*)d_in[18];

    float* out   = (float*)d_out;
    float* alpha = out;                       // 12800
    float* h_seq = out + 12800;               // 1,638,400
    float* C_out = out + 12800 + 1638400;     // 25,600,000
    float* ws    = (float*)d_ws;

    hipLaunchKernelGGL(pre_kernel, dim3(2), dim3(256), 0, stream,
                       v_d, v_r, v_c, W_ih, W2a, ws);
    hipLaunchKernelGGL(fused_kernel, dim3(NGRU + BB), dim3(512), 0, stream,
                       c_seq, d_seq, r_seq, D_emb, W_hh, b_ih, b_hh,
                       W2b, b2a, b2b, ws, C_out, h_seq);
    hipLaunchKernelGGL(alpha_kernel, dim3(100), dim3(512), 0, stream,
                       h_seq, W1a, b1a, W1b, b1b, alpha);
}

// Round 27
// 115.638 us; speedup vs baseline: 1.1801x; 1.0097x over previous
//
#include <hip/hip_runtime.h>
#include <hip/hip_bf16.h>
#include <cstdint>

#define BB 64
#define TT 200
#define KN 2000
#define VV 128
#define NGRU 16   // GRU blocks; each handles 4 batch rows

typedef __attribute__((ext_vector_type(8))) short bf16x8;
typedef __attribute__((ext_vector_type(4))) float f32x4;
typedef _Float16 half8 __attribute__((ext_vector_type(8)));

// ws layout (floats): pd[384]@0, pr[384]@384, uc[128]@768, ud[128]@896, ur[128]@1024
// r18: projections can't be per-block dot128 preambles (+41us, uncoalesced).
// r23: alpha must stay a separate 100-block dispatch.
// r26 CRITICAL: single-buffer H_half had a cross-wave WAR race (fast wave's
// h_t write vs slow wave's h_{t-1} read in the same barrier interval) --
// passed ~15 runs then failed a replay. Fix: double-buffer H (read t&1,
// write (t&1)^1). This also explains r25's "inexplicable" failure.

// r11/r13: IEEE divides were the gate chain; rcp forms (~1ulp) are fine.
__device__ __forceinline__ float sigm(float x) {
    return __builtin_amdgcn_rcpf(1.f + __expf(-x));
}
__device__ __forceinline__ float tanh_f(float x) {
    float e = __expf(2.f * x);
    return 1.f - 2.f * __builtin_amdgcn_rcpf(e + 1.f);
}

// r17: LDS spin barriers lose 3x to s_barrier. r20-r22: r19 scan structure is
// the local optimum (wave count / per-wave work / chain depth / LDS isolated).
__device__ __forceinline__ void soft_barrier() {
    asm volatile("s_waitcnt lgkmcnt(0)" ::: "memory");
    __builtin_amdgcn_s_barrier();
    __builtin_amdgcn_sched_barrier(0);
}

// ---------------- precompute: small projection vectors (once, chip-wide) -----
__global__ void pre_kernel(const float* __restrict__ v_d, const float* __restrict__ v_r,
                           const float* __restrict__ v_c, const float* __restrict__ W_ih,
                           const float* __restrict__ W2a, float* __restrict__ ws)
{
    int g = blockIdx.x * 256 + threadIdx.x;   // grid 2 x 256 = 512 threads
    float* pd = ws;
    float* pr = ws + 384;
    float* uc = ws + 768;
    float* ud = ws + 896;
    float* ur = ws + 1024;
    if (g < 384) {
        float a = 0.f, b = 0.f;
        for (int k = 0; k < VV; ++k) {
            a = fmaf(W_ih[g * 256 + k], v_d[k], a);
            b = fmaf(W_ih[g * 256 + VV + k], v_r[k], b);
        }
        pd[g] = a; pr[g] = b;
    }
    if (g < VV) {
        float a = 0.f, b = 0.f, c = 0.f;
        for (int k = 0; k < VV; ++k) {
            a = fmaf(W2a[g * 384 + k], v_c[k], a);
            b = fmaf(W2a[g * 384 + VV + k], v_d[k], b);
            c = fmaf(W2a[g * 384 + 2 * VV + k], v_r[k], c);
        }
        uc[g] = a; ud[g] = b; ur[g] = c;
    }
}

__device__ __forceinline__ half8 load_cvt8h(const float* p) {
    float4 a = *(const float4*)p;
    float4 c = *(const float4*)(p + 4);
    half8 r;
    r[0] = (_Float16)a.x; r[1] = (_Float16)a.y; r[2] = (_Float16)a.z; r[3] = (_Float16)a.w;
    r[4] = (_Float16)c.x; r[5] = (_Float16)c.y; r[6] = (_Float16)c.z; r[7] = (_Float16)c.w;
    return r;
}

// ---------------- fused: blocks 0-15 GRU (4 rows each, MFMA), 16-79 mem scan --
// r19 structure + H double-buffer race fix. 16 blocks x 4 batch rows at MFMA
// rows ≡0 mod 4, lane gq's acc[0] is the single valid row -> 1-row GATE.
__global__ __launch_bounds__(512, 1) void fused_kernel(
    const int* __restrict__ c_seq, const int* __restrict__ d_seq,
    const float* __restrict__ r_seq, const float* __restrict__ D_emb,
    const float* __restrict__ Whh, const float* __restrict__ bih,
    const float* __restrict__ bhh, const float* __restrict__ W2b,
    const float* __restrict__ b2a, const float* __restrict__ b2b,
    const float* __restrict__ ws, float* __restrict__ C_out,
    float* __restrict__ h_out)
{
    __shared__ __align__(16) _Float16 Hbuf[2][16 * 136];  // dbuf: read t&1, write ^1
    __shared__ __align__(8) float gam4[TT * 4], r4[TT * 4];  // [t][rr]
    __shared__ __align__(16) float C[KN];
    __shared__ float gam_row[TT], r_row[TT], n_row[TT];
    __shared__ int c_row[TT + 1];

    int tid = threadIdx.x;

    if (blockIdx.x < NGRU) {
        // ================= GRU path: 4 batch rows =================
        int b0 = blockIdx.x * 4;
        const float* pd = ws;
        const float* pr = ws + 384;

        for (int i = tid; i < TT * 4; i += 512) {
            int t = i >> 2, rr = i & 3;
            gam4[i] = D_emb[d_seq[(b0 + rr) * TT + t]];
            r4[i] = r_seq[(b0 + rr) * TT + t];
        }
        for (int i = tid; i < 2 * 16 * 136; i += 512)
            ((_Float16*)Hbuf)[i] = (_Float16)0.f;

        int wid = tid >> 6, l = tid & 63;
        int cl = l & 15, gq = l >> 4;
        int nn = wid * 16 + cl;      // output col (0..127)
        // batch row this lane owns: b0+gq, at MFMA row gq*4 (acc[0]).

        // B-fragments: 12 frags = 48 regs, resident (r9: FETCH 590KB confirmed)
        const float* wr = Whh + (size_t)nn * VV + gq * 8;
        const float* wz = Whh + (size_t)(nn + 128) * VV + gq * 8;
        const float* wn = Whh + (size_t)(nn + 256) * VV + gq * 8;
        half8 br0 = load_cvt8h(wr),      br1 = load_cvt8h(wr + 32),
              br2 = load_cvt8h(wr + 64), br3 = load_cvt8h(wr + 96);
        half8 bz0 = load_cvt8h(wz),      bz1 = load_cvt8h(wz + 32),
              bz2 = load_cvt8h(wz + 64), bz3 = load_cvt8h(wz + 96);
        half8 bn0 = load_cvt8h(wn),      bn1 = load_cvt8h(wn + 32),
              bn2 = load_cvt8h(wn + 64), bn3 = load_cvt8h(wn + 96);

        // per-lane gi fold scalars from ws (col nn fixed per lane)
        float gr_pd = pd[nn],        gr_pr = pr[nn],        gr_b = bih[nn] + bhh[nn];
        float gz_pd = pd[nn + 128],  gz_pr = pr[nn + 128],  gz_b = bih[nn + 128] + bhh[nn + 128];
        float gn_pd = pd[nn + 256],  gn_pr = pr[nn + 256],  gn_b = bih[nn + 256];
        float gn_bh = bhh[nn + 256];

        float h0 = 0.f;
        __syncthreads();   // setup barrier

        for (int t = 0; t < TT; ++t) {
            asm volatile("" : "+v"(br0), "+v"(br1), "+v"(br2), "+v"(br3),
                              "+v"(bz0), "+v"(bz1), "+v"(bz2), "+v"(bz3),
                              "+v"(bn0), "+v"(bn1), "+v"(bn2), "+v"(bn3));
            const _Float16* Hr = Hbuf[t & 1];
            _Float16* Hw = Hbuf[(t & 1) ^ 1];
            // A-fragments + per-step scalars (fold overlaps ds_read latency)
            const int ab = cl * 136 + gq * 8;
            half8 a0 = *(const half8*)&Hr[ab];
            half8 a1 = *(const half8*)&Hr[ab + 32];
            half8 a2 = *(const half8*)&Hr[ab + 64];
            half8 a3 = *(const half8*)&Hr[ab + 96];
            float g1 = gam4[t * 4 + gq];
            float q1 = r4[t * 4 + gq];

            // gi fold as MFMA C-in (only acc[0] meaningful)
            f32x4 accr = {0.f, 0.f, 0.f, 0.f};
            f32x4 accz = {0.f, 0.f, 0.f, 0.f};
            f32x4 accn = {0.f, 0.f, 0.f, 0.f};
            accr[0] = fmaf(g1, gr_pd, fmaf(q1, gr_pr, gr_b));
            accz[0] = fmaf(g1, gz_pd, fmaf(q1, gz_pr, gz_b));
            accn[0] = gn_bh;
            float gin0 = fmaf(g1, gn_pd, fmaf(q1, gn_pr, gn_b));

            accr = __builtin_amdgcn_mfma_f32_16x16x32_f16(a0, br0, accr, 0, 0, 0);
            accr = __builtin_amdgcn_mfma_f32_16x16x32_f16(a1, br1, accr, 0, 0, 0);
            accr = __builtin_amdgcn_mfma_f32_16x16x32_f16(a2, br2, accr, 0, 0, 0);
            accr = __builtin_amdgcn_mfma_f32_16x16x32_f16(a3, br3, accr, 0, 0, 0);
            accz = __builtin_amdgcn_mfma_f32_16x16x32_f16(a0, bz0, accz, 0, 0, 0);
            accz = __builtin_amdgcn_mfma_f32_16x16x32_f16(a1, bz1, accz, 0, 0, 0);
            accz = __builtin_amdgcn_mfma_f32_16x16x32_f16(a2, bz2, accz, 0, 0, 0);
            accz = __builtin_amdgcn_mfma_f32_16x16x32_f16(a3, bz3, accz, 0, 0, 0);
            accn = __builtin_amdgcn_mfma_f32_16x16x32_f16(a0, bn0, accn, 0, 0, 0);
            accn = __builtin_amdgcn_mfma_f32_16x16x32_f16(a1, bn1, accn, 0, 0, 0);
            accn = __builtin_amdgcn_mfma_f32_16x16x32_f16(a2, bn2, accn, 0, 0, 0);
            accn = __builtin_amdgcn_mfma_f32_16x16x32_f16(a3, bn3, accn, 0, 0, 0);

            // gate: acc[0] = (batch row b0+gq, col nn), lane-local
            {
                float rg0 = sigm(accr[0]);
                float zg0 = sigm(accz[0]);
                float ng0 = tanh_f(fmaf(rg0, accn[0], gin0));
                h0 = fmaf(1.f - zg0, ng0, zg0 * h0);
                Hw[(gq * 4) * 136 + nn] = (_Float16)h0;   // write buffer != read buffer
                h_out[((size_t)(b0 + gq) * TT + t) * VV + nn] = h0;
            }
            soft_barrier();   // LDS Hw visibility; h_out stays in flight
        }
    } else {
        // ================= memory-scan path: 2 phases =================
        int b = blockIdx.x - NGRU;
        const float* uc = ws + 768;
        const float* ud = ws + 896;
        const float* ur = ws + 1024;
        for (int i = tid; i < KN; i += 512) C[i] = 0.f;
        if (tid < TT) {
            gam_row[tid] = D_emb[d_seq[b * TT + tid]];
            r_row[tid] = r_seq[b * TT + tid];
            c_row[tid] = c_seq[b * TT + tid];
        }
        if (tid == 0) c_row[TT] = 0;
        __syncthreads();

        // ---- phase 1: wave0 scans; C[c(t+1)] prefetch + select ----
        if (tid < 64) {
            int l = tid;
            float uc0 = uc[l], uc1 = uc[l + 64];
            float ud0 = ud[l], ud1 = ud[l + 64];
            float ur0 = ur[l], ur1 = ur[l + 64];
            float ba0 = b2a[l], ba1 = b2a[l + 64];
            float wb0 = W2b[l], wb1 = W2b[l + 64];
            float bb = b2b[0];
            float beta = 0.f;
            int ct = c_row[0];
            for (int t = 0; t < TT; ++t) {
                int ct1 = c_row[t + 1];
                float cpref = C[ct1];
                float g = gam_row[t], rr = r_row[t];
                float hh0 = fmaxf(fmaf(beta, uc0, fmaf(g, ud0, fmaf(rr, ur0, ba0))), 0.f);
                float hh1 = fmaxf(fmaf(beta, uc1, fmaf(g, ud1, fmaf(rr, ur1, ba1))), 0.f);
                float p = fmaf(hh0, wb0, hh1 * wb1);
                #pragma unroll
                for (int m = 32; m > 0; m >>= 1) p += __shfl_xor(p, m);
                float nc = p + bb;
                if (l == 0) { C[ct] = nc; n_row[t] = nc; }
                beta = (ct1 == ct) ? nc : cpref;
                ct = ct1;
            }
        }
        __syncthreads();

        // ---- phase 2: all 8 waves reconstruct C_out (float4/lane) ----
        int k0 = tid * 4;
        if (k0 < KN) {
            float4 cur = {0.f, 0.f, 0.f, 0.f};
            float* cop = C_out + (size_t)b * TT * KN + k0;
            for (int t = 0; t < TT; ++t) {
                int c = c_row[t];
                unsigned d = (unsigned)(c - k0);
                if (d < 4u) {
                    float v = n_row[t];
                    cur.x = (d == 0u) ? v : cur.x;
                    cur.y = (d == 1u) ? v : cur.y;
                    cur.z = (d == 2u) ? v : cur.z;
                    cur.w = (d == 3u) ? v : cur.w;
                }
                *(float4*)(cop + (size_t)t * KN) = cur;
            }
        }
    }
}

// ---------------- alpha head: W1a staged in LDS (padded), bf16 MFMA ----------
__device__ __forceinline__ short f2bf(float f) {
    uint32_t u = __float_as_uint(f);
    u = (u + 0x7FFFu + ((u >> 16) & 1u)) >> 16;
    return (short)u;
}
__device__ __forceinline__ bf16x8 load_cvt8(const float* p) {
    float4 a = *(const float4*)p;
    float4 c = *(const float4*)(p + 4);
    bf16x8 r;
    r[0] = f2bf(a.x); r[1] = f2bf(a.y); r[2] = f2bf(a.z); r[3] = f2bf(a.w);
    r[4] = f2bf(c.x); r[5] = f2bf(c.y); r[6] = f2bf(c.z); r[7] = f2bf(c.w);
    return r;
}

__global__ __launch_bounds__(512) void alpha_kernel(
    const float* __restrict__ h_seq, const float* __restrict__ W1a,
    const float* __restrict__ b1a, const float* __restrict__ W1b,
    const float* __restrict__ b1b, float* __restrict__ alpha)
{
    __shared__ __align__(16) short W1s[128 * 136];   // bf16, padded stride 136
    __shared__ float b1s[128], w1bs[128];
    int tid = threadIdx.x;
    for (int i = tid * 8; i < 128 * 128; i += 512 * 8) {
        int row = i >> 7, col = i & 127;
        *(bf16x8*)&W1s[row * 136 + col] = load_cvt8(W1a + i);
    }
    if (tid < 128) { b1s[tid] = b1a[tid]; w1bs[tid] = W1b[tid]; }
    __syncthreads();

    int wave = tid >> 6, lane = tid & 63;
    int tile = blockIdx.x * 8 + wave;      // 800 tiles of 16 rows, 100 blocks
    int rowbase = tile * 16;
    int rl = lane & 15, g = lane >> 4;
    const float* hp = h_seq + (size_t)(rowbase + rl) * VV + g * 8;
    bf16x8 a0 = load_cvt8(hp);
    bf16x8 a1 = load_cvt8(hp + 32);
    bf16x8 a2 = load_cvt8(hp + 64);
    bf16x8 a3 = load_cvt8(hp + 96);
    float p0 = 0.f, p1 = 0.f, p2 = 0.f, p3 = 0.f;
    float bb = b1b[0];
    #pragma unroll
    for (int jt = 0; jt < 8; ++jt) {
        int j = jt * 16 + rl;
        const short* wp = &W1s[j * 136 + g * 8];
        f32x4 acc = {0.f, 0.f, 0.f, 0.f};
        acc = __builtin_amdgcn_mfma_f32_16x16x32_bf16(a0, *(const bf16x8*)wp, acc, 0, 0, 0);
        acc = __builtin_amdgcn_mfma_f32_16x16x32_bf16(a1, *(const bf16x8*)(wp + 32), acc, 0, 0, 0);
        acc = __builtin_amdgcn_mfma_f32_16x16x32_bf16(a2, *(const bf16x8*)(wp + 64), acc, 0, 0, 0);
        acc = __builtin_amdgcn_mfma_f32_16x16x32_bf16(a3, *(const bf16x8*)(wp + 96), acc, 0, 0, 0);
        float bj = b1s[j], wj = w1bs[j];
        p0 += fmaxf(acc[0] + bj, 0.f) * wj;
        p1 += fmaxf(acc[1] + bj, 0.f) * wj;
        p2 += fmaxf(acc[2] + bj, 0.f) * wj;
        p3 += fmaxf(acc[3] + bj, 0.f) * wj;
    }
    #pragma unroll
    for (int m = 1; m < 16; m <<= 1) {
        p0 += __shfl_xor(p0, m);
        p1 += __shfl_xor(p1, m);
        p2 += __shfl_xor(p2, m);
        p3 += __shfl_xor(p3, m);
    }
    if (rl == 0) {
        alpha[rowbase + g * 4 + 0] = p0 + bb;
        alpha[rowbase + g * 4 + 1] = p1 + bb;
        alpha[rowbase + g * 4 + 2] = p2 + bb;
        alpha[rowbase + g * 4 + 3] = p3 + bb;
    }
}

extern "C" void kernel_launch(void* const* d_in, const int* in_sizes, int n_in,
                              void* d_out, int out_size, void* d_ws, size_t ws_size,
                              hipStream_t stream)
{
    const int*   c_seq = (const int*)d_in[0];
    const int*   d_seq = (const int*)d_in[1];
    const float* r_seq = (const float*)d_in[2];
    const float* D_emb = (const float*)d_in[3];
    const float* v_d   = (const float*)d_in[4];
    const float* v_r   = (const float*)d_in[5];
    const float* v_c   = (const float*)d_in[6];
    const float* W_ih  = (const float*)d_in[7];
    const float* W_hh  = (const float*)d_in[8];
    const float* b_ih  = (const float*)d_in[9];
    const float* b_hh  = (const float*)d_in[10];
    const float* W1a   = (const float*)d_in[11];
    const float* b1a   = (const float*)d_in[12];
    const float* W1b   = (const float*)d_in[13];
    const float* b1b   = (const float*)d_in[14];
    const float* W2a   = (const float*)d_in[15];
    const float* b2a   = (const float*)d_in[16];
    const float* W2b   = (const float*)d_in[17];
    const float* b2b   = (const float*)d_in[18];

    float* out   = (float*)d_out;
    float* alpha = out;                       // 12800
    float* h_seq = out + 12800;               // 1,638,400
    float* C_out = out + 12800 + 1638400;     // 25,600,000
    float* ws    = (float*)d_ws;

    hipLaunchKernelGGL(pre_kernel, dim3(2), dim3(256), 0, stream,
                       v_d, v_r, v_c, W_ih, W2a, ws);
    hipLaunchKernelGGL(fused_kernel, dim3(NGRU + BB), dim3(512), 0, stream,
                       c_seq, d_seq, r_seq, D_emb, W_hh, b_ih, b_hh,
                       W2b, b2a, b2b, ws, C_out, h_seq);
    hipLaunchKernelGGL(alpha_kernel, dim3(100), dim3(512), 0, stream,
                       h_seq, W1a, b1a, W1b, b1b, alpha);
}

// Round 28
// 99.156 us; speedup vs baseline: 1.3762x; 1.1662x over previous
//
#include <hip/hip_runtime.h>
#include <hip/hip_bf16.h>
#include <cstdint>

#define BB 64
#define TT 200
#define KN 2000
#define VV 128
#define NGRU 16   // GRU blocks; each handles 4 batch rows

typedef __attribute__((ext_vector_type(8))) short bf16x8;
typedef __attribute__((ext_vector_type(4))) float f32x4;
typedef _Float16 half8 __attribute__((ext_vector_type(8)));

// ws layout (floats): pd[384]@0, pr[384]@384, uc[128]@768, ud[128]@896, ur[128]@1024
// r18: projections can't be per-block dot128 preambles (+41us, uncoalesced).
// r23: alpha must stay a separate 100-block dispatch.
// r26: single-buffer H had a cross-wave WAR race -> double-buffer (fixed, r27
// passed at 115.6us). r25's wave-per-dot pre failure is re-attributed to that
// race (timing perturbation); mapping re-audited clean -> retrying it here.

// r11/r13: IEEE divides were the gate chain; rcp forms (~1ulp) are fine.
__device__ __forceinline__ float sigm(float x) {
    return __builtin_amdgcn_rcpf(1.f + __expf(-x));
}
__device__ __forceinline__ float tanh_f(float x) {
    float e = __expf(2.f * x);
    return 1.f - 2.f * __builtin_amdgcn_rcpf(e + 1.f);
}

// r17: LDS spin barriers lose 3x to s_barrier. r20-r22: r19 scan structure is
// the local optimum (wave count / per-wave work / chain depth / LDS isolated).
__device__ __forceinline__ void soft_barrier() {
    asm volatile("s_waitcnt lgkmcnt(0)" ::: "memory");
    __builtin_amdgcn_s_barrier();
    __builtin_amdgcn_sched_barrier(0);
}

// ---------------- precompute: wave-per-dot, fully coalesced ------------------
// 1152 dots: pd[0:384), pr[0:384), uc[0:128), ud[0:128), ur[0:128).
// One wave per dot: lane k reads float2 of the weight row (512B/wave,
// coalesced) + float2 of v, fma, 6-step shuffle reduce, lane 0 writes.
// (r24 audit: the serial 2-block version cost ~20us on 2 CUs.)
__global__ __launch_bounds__(512) void pre_kernel(
    const float* __restrict__ v_d, const float* __restrict__ v_r,
    const float* __restrict__ v_c, const float* __restrict__ W_ih,
    const float* __restrict__ W2a, float* __restrict__ ws)
{
    int gw = (blockIdx.x * 512 + threadIdx.x) >> 6;   // global wave id 0..1151
    int lane = threadIdx.x & 63;
    const float* wrow;
    const float* vvec;
    if (gw < 384) {
        wrow = W_ih + (size_t)gw * 256;               vvec = v_d;
    } else if (gw < 768) {
        wrow = W_ih + (size_t)(gw - 384) * 256 + 128; vvec = v_r;
    } else if (gw < 896) {
        wrow = W2a + (size_t)(gw - 768) * 384;        vvec = v_c;
    } else if (gw < 1024) {
        wrow = W2a + (size_t)(gw - 896) * 384 + 128;  vvec = v_d;
    } else {
        wrow = W2a + (size_t)(gw - 1024) * 384 + 256; vvec = v_r;
    }
    float2 wv = *(const float2*)(wrow + lane * 2);
    float2 vv = *(const float2*)(vvec + lane * 2);
    float p = fmaf(wv.x, vv.x, wv.y * vv.y);
    #pragma unroll
    for (int m = 32; m > 0; m >>= 1) p += __shfl_xor(p, m);
    if (lane == 0) ws[gw] = p;   // dst == gw across all 5 sections
}

__device__ __forceinline__ half8 load_cvt8h(const float* p) {
    float4 a = *(const float4*)p;
    float4 c = *(const float4*)(p + 4);
    half8 r;
    r[0] = (_Float16)a.x; r[1] = (_Float16)a.y; r[2] = (_Float16)a.z; r[3] = (_Float16)a.w;
    r[4] = (_Float16)c.x; r[5] = (_Float16)c.y; r[6] = (_Float16)c.z; r[7] = (_Float16)c.w;
    return r;
}

// ---------------- fused: blocks 0-15 GRU (4 rows each, MFMA), 16-79 mem scan --
// r19 structure + H double-buffer race fix (r27 proven, 115.6us total).
__global__ __launch_bounds__(512, 1) void fused_kernel(
    const int* __restrict__ c_seq, const int* __restrict__ d_seq,
    const float* __restrict__ r_seq, const float* __restrict__ D_emb,
    const float* __restrict__ Whh, const float* __restrict__ bih,
    const float* __restrict__ bhh, const float* __restrict__ W2b,
    const float* __restrict__ b2a, const float* __restrict__ b2b,
    const float* __restrict__ ws, float* __restrict__ C_out,
    float* __restrict__ h_out)
{
    __shared__ __align__(16) _Float16 Hbuf[2][16 * 136];  // dbuf: read t&1, write ^1
    __shared__ __align__(8) float gam4[TT * 4], r4[TT * 4];  // [t][rr]
    __shared__ __align__(16) float C[KN];
    __shared__ float gam_row[TT], r_row[TT], n_row[TT];
    __shared__ int c_row[TT + 1];

    int tid = threadIdx.x;

    if (blockIdx.x < NGRU) {
        // ================= GRU path: 4 batch rows =================
        int b0 = blockIdx.x * 4;
        const float* pd = ws;
        const float* pr = ws + 384;

        for (int i = tid; i < TT * 4; i += 512) {
            int t = i >> 2, rr = i & 3;
            gam4[i] = D_emb[d_seq[(b0 + rr) * TT + t]];
            r4[i] = r_seq[(b0 + rr) * TT + t];
        }
        for (int i = tid; i < 2 * 16 * 136; i += 512)
            ((_Float16*)Hbuf)[i] = (_Float16)0.f;

        int wid = tid >> 6, l = tid & 63;
        int cl = l & 15, gq = l >> 4;
        int nn = wid * 16 + cl;      // output col (0..127)
        // batch row this lane owns: b0+gq, at MFMA row gq*4 (acc[0]).

        // B-fragments: 12 frags = 48 regs, resident (r9: FETCH 590KB confirmed)
        const float* wr = Whh + (size_t)nn * VV + gq * 8;
        const float* wz = Whh + (size_t)(nn + 128) * VV + gq * 8;
        const float* wn = Whh + (size_t)(nn + 256) * VV + gq * 8;
        half8 br0 = load_cvt8h(wr),      br1 = load_cvt8h(wr + 32),
              br2 = load_cvt8h(wr + 64), br3 = load_cvt8h(wr + 96);
        half8 bz0 = load_cvt8h(wz),      bz1 = load_cvt8h(wz + 32),
              bz2 = load_cvt8h(wz + 64), bz3 = load_cvt8h(wz + 96);
        half8 bn0 = load_cvt8h(wn),      bn1 = load_cvt8h(wn + 32),
              bn2 = load_cvt8h(wn + 64), bn3 = load_cvt8h(wn + 96);

        // per-lane gi fold scalars from ws (col nn fixed per lane)
        float gr_pd = pd[nn],        gr_pr = pr[nn],        gr_b = bih[nn] + bhh[nn];
        float gz_pd = pd[nn + 128],  gz_pr = pr[nn + 128],  gz_b = bih[nn + 128] + bhh[nn + 128];
        float gn_pd = pd[nn + 256],  gn_pr = pr[nn + 256],  gn_b = bih[nn + 256];
        float gn_bh = bhh[nn + 256];

        float h0 = 0.f;
        __syncthreads();   // setup barrier

        for (int t = 0; t < TT; ++t) {
            asm volatile("" : "+v"(br0), "+v"(br1), "+v"(br2), "+v"(br3),
                              "+v"(bz0), "+v"(bz1), "+v"(bz2), "+v"(bz3),
                              "+v"(bn0), "+v"(bn1), "+v"(bn2), "+v"(bn3));
            const _Float16* Hr = Hbuf[t & 1];
            _Float16* Hw = Hbuf[(t & 1) ^ 1];
            // A-fragments + per-step scalars (fold overlaps ds_read latency)
            const int ab = cl * 136 + gq * 8;
            half8 a0 = *(const half8*)&Hr[ab];
            half8 a1 = *(const half8*)&Hr[ab + 32];
            half8 a2 = *(const half8*)&Hr[ab + 64];
            half8 a3 = *(const half8*)&Hr[ab + 96];
            float g1 = gam4[t * 4 + gq];
            float q1 = r4[t * 4 + gq];

            // gi fold as MFMA C-in (only acc[0] meaningful)
            f32x4 accr = {0.f, 0.f, 0.f, 0.f};
            f32x4 accz = {0.f, 0.f, 0.f, 0.f};
            f32x4 accn = {0.f, 0.f, 0.f, 0.f};
            accr[0] = fmaf(g1, gr_pd, fmaf(q1, gr_pr, gr_b));
            accz[0] = fmaf(g1, gz_pd, fmaf(q1, gz_pr, gz_b));
            accn[0] = gn_bh;
            float gin0 = fmaf(g1, gn_pd, fmaf(q1, gn_pr, gn_b));

            accr = __builtin_amdgcn_mfma_f32_16x16x32_f16(a0, br0, accr, 0, 0, 0);
            accr = __builtin_amdgcn_mfma_f32_16x16x32_f16(a1, br1, accr, 0, 0, 0);
            accr = __builtin_amdgcn_mfma_f32_16x16x32_f16(a2, br2, accr, 0, 0, 0);
            accr = __builtin_amdgcn_mfma_f32_16x16x32_f16(a3, br3, accr, 0, 0, 0);
            accz = __builtin_amdgcn_mfma_f32_16x16x32_f16(a0, bz0, accz, 0, 0, 0);
            accz = __builtin_amdgcn_mfma_f32_16x16x32_f16(a1, bz1, accz, 0, 0, 0);
            accz = __builtin_amdgcn_mfma_f32_16x16x32_f16(a2, bz2, accz, 0, 0, 0);
            accz = __builtin_amdgcn_mfma_f32_16x16x32_f16(a3, bz3, accz, 0, 0, 0);
            accn = __builtin_amdgcn_mfma_f32_16x16x32_f16(a0, bn0, accn, 0, 0, 0);
            accn = __builtin_amdgcn_mfma_f32_16x16x32_f16(a1, bn1, accn, 0, 0, 0);
            accn = __builtin_amdgcn_mfma_f32_16x16x32_f16(a2, bn2, accn, 0, 0, 0);
            accn = __builtin_amdgcn_mfma_f32_16x16x32_f16(a3, bn3, accn, 0, 0, 0);

            // gate: acc[0] = (batch row b0+gq, col nn), lane-local
            {
                float rg0 = sigm(accr[0]);
                float zg0 = sigm(accz[0]);
                float ng0 = tanh_f(fmaf(rg0, accn[0], gin0));
                h0 = fmaf(1.f - zg0, ng0, zg0 * h0);
                Hw[(gq * 4) * 136 + nn] = (_Float16)h0;   // write buffer != read buffer
                h_out[((size_t)(b0 + gq) * TT + t) * VV + nn] = h0;
            }
            soft_barrier();   // LDS Hw visibility; h_out stays in flight
        }
    } else {
        // ================= memory-scan path: 2 phases =================
        int b = blockIdx.x - NGRU;
        const float* uc = ws + 768;
        const float* ud = ws + 896;
        const float* ur = ws + 1024;
        for (int i = tid; i < KN; i += 512) C[i] = 0.f;
        if (tid < TT) {
            gam_row[tid] = D_emb[d_seq[b * TT + tid]];
            r_row[tid] = r_seq[b * TT + tid];
            c_row[tid] = c_seq[b * TT + tid];
        }
        if (tid == 0) c_row[TT] = 0;
        __syncthreads();

        // ---- phase 1: wave0 scans; C[c(t+1)] prefetch + select ----
        if (tid < 64) {
            int l = tid;
            float uc0 = uc[l], uc1 = uc[l + 64];
            float ud0 = ud[l], ud1 = ud[l + 64];
            float ur0 = ur[l], ur1 = ur[l + 64];
            float ba0 = b2a[l], ba1 = b2a[l + 64];
            float wb0 = W2b[l], wb1 = W2b[l + 64];
            float bb = b2b[0];
            float beta = 0.f;
            int ct = c_row[0];
            for (int t = 0; t < TT; ++t) {
                int ct1 = c_row[t + 1];
                float cpref = C[ct1];
                float g = gam_row[t], rr = r_row[t];
                float hh0 = fmaxf(fmaf(beta, uc0, fmaf(g, ud0, fmaf(rr, ur0, ba0))), 0.f);
                float hh1 = fmaxf(fmaf(beta, uc1, fmaf(g, ud1, fmaf(rr, ur1, ba1))), 0.f);
                float p = fmaf(hh0, wb0, hh1 * wb1);
                #pragma unroll
                for (int m = 32; m > 0; m >>= 1) p += __shfl_xor(p, m);
                float nc = p + bb;
                if (l == 0) { C[ct] = nc; n_row[t] = nc; }
                beta = (ct1 == ct) ? nc : cpref;
                ct = ct1;
            }
        }
        __syncthreads();

        // ---- phase 2: all 8 waves reconstruct C_out (float4/lane) ----
        int k0 = tid * 4;
        if (k0 < KN) {
            float4 cur = {0.f, 0.f, 0.f, 0.f};
            float* cop = C_out + (size_t)b * TT * KN + k0;
            for (int t = 0; t < TT; ++t) {
                int c = c_row[t];
                unsigned d = (unsigned)(c - k0);
                if (d < 4u) {
                    float v = n_row[t];
                    cur.x = (d == 0u) ? v : cur.x;
                    cur.y = (d == 1u) ? v : cur.y;
                    cur.z = (d == 2u) ? v : cur.z;
                    cur.w = (d == 3u) ? v : cur.w;
                }
                *(float4*)(cop + (size_t)t * KN) = cur;
            }
        }
    }
}

// ---------------- alpha head: W1a staged in LDS (padded), bf16 MFMA ----------
__device__ __forceinline__ short f2bf(float f) {
    uint32_t u = __float_as_uint(f);
    u = (u + 0x7FFFu + ((u >> 16) & 1u)) >> 16;
    return (short)u;
}
__device__ __forceinline__ bf16x8 load_cvt8(const float* p) {
    float4 a = *(const float4*)p;
    float4 c = *(const float4*)(p + 4);
    bf16x8 r;
    r[0] = f2bf(a.x); r[1] = f2bf(a.y); r[2] = f2bf(a.z); r[3] = f2bf(a.w);
    r[4] = f2bf(c.x); r[5] = f2bf(c.y); r[6] = f2bf(c.z); r[7] = f2bf(c.w);
    return r;
}

__global__ __launch_bounds__(512) void alpha_kernel(
    const float* __restrict__ h_seq, const float* __restrict__ W1a,
    const float* __restrict__ b1a, const float* __restrict__ W1b,
    const float* __restrict__ b1b, float* __restrict__ alpha)
{
    __shared__ __align__(16) short W1s[128 * 136];   // bf16, padded stride 136
    __shared__ float b1s[128], w1bs[128];
    int tid = threadIdx.x;
    for (int i = tid * 8; i < 128 * 128; i += 512 * 8) {
        int row = i >> 7, col = i & 127;
        *(bf16x8*)&W1s[row * 136 + col] = load_cvt8(W1a + i);
    }
    if (tid < 128) { b1s[tid] = b1a[tid]; w1bs[tid] = W1b[tid]; }
    __syncthreads();

    int wave = tid >> 6, lane = tid & 63;
    int tile = blockIdx.x * 8 + wave;      // 800 tiles of 16 rows, 100 blocks
    int rowbase = tile * 16;
    int rl = lane & 15, g = lane >> 4;
    const float* hp = h_seq + (size_t)(rowbase + rl) * VV + g * 8;
    bf16x8 a0 = load_cvt8(hp);
    bf16x8 a1 = load_cvt8(hp + 32);
    bf16x8 a2 = load_cvt8(hp + 64);
    bf16x8 a3 = load_cvt8(hp + 96);
    float p0 = 0.f, p1 = 0.f, p2 = 0.f, p3 = 0.f;
    float bb = b1b[0];
    #pragma unroll
    for (int jt = 0; jt < 8; ++jt) {
        int j = jt * 16 + rl;
        const short* wp = &W1s[j * 136 + g * 8];
        f32x4 acc = {0.f, 0.f, 0.f, 0.f};
        acc = __builtin_amdgcn_mfma_f32_16x16x32_bf16(a0, *(const bf16x8*)wp, acc, 0, 0, 0);
        acc = __builtin_amdgcn_mfma_f32_16x16x32_bf16(a1, *(const bf16x8*)(wp + 32), acc, 0, 0, 0);
        acc = __builtin_amdgcn_mfma_f32_16x16x32_bf16(a2, *(const bf16x8*)(wp + 64), acc, 0, 0, 0);
        acc = __builtin_amdgcn_mfma_f32_16x16x32_bf16(a3, *(const bf16x8*)(wp + 96), acc, 0, 0, 0);
        float bj = b1s[j], wj = w1bs[j];
        p0 += fmaxf(acc[0] + bj, 0.f) * wj;
        p1 += fmaxf(acc[1] + bj, 0.f) * wj;
        p2 += fmaxf(acc[2] + bj, 0.f) * wj;
        p3 += fmaxf(acc[3] + bj, 0.f) * wj;
    }
    #pragma unroll
    for (int m = 1; m < 16; m <<= 1) {
        p0 += __shfl_xor(p0, m);
        p1 += __shfl_xor(p1, m);
        p2 += __shfl_xor(p2, m);
        p3 += __shfl_xor(p3, m);
    }
    if (rl == 0) {
        alpha[rowbase + g * 4 + 0] = p0 + bb;
        alpha[rowbase + g * 4 + 1] = p1 + bb;
        alpha[rowbase + g * 4 + 2] = p2 + bb;
        alpha[rowbase + g * 4 + 3] = p3 + bb;
    }
}

extern "C" void kernel_launch(void* const* d_in, const int* in_sizes, int n_in,
                              void* d_out, int out_size, void* d_ws, size_t ws_size,
                              hipStream_t stream)
{
    const int*   c_seq = (const int*)d_in[0];
    const int*   d_seq = (const int*)d_in[1];
    const float* r_seq = (const float*)d_in[2];
    const float* D_emb = (const float*)d_in[3];
    const float* v_d   = (const float*)d_in[4];
    const float* v_r   = (const float*)d_in[5];
    const float* v_c   = (const float*)d_in[6];
    const float* W_ih  = (const float*)d_in[7];
    const float* W_hh  = (const float*)d_in[8];
    const float* b_ih  = (const float*)d_in[9];
    const float* b_hh  = (const float*)d_in[10];
    const float* W1a   = (const float*)d_in[11];
    const float* b1a   = (const float*)d_in[12];
    const float* W1b   = (const float*)d_in[13];
    const float* b1b   = (const float*)d_in[14];
    const float* W2a   = (const float*)d_in[15];
    const float* b2a   = (const float*)d_in[16];
    const float* W2b   = (const float*)d_in[17];
    const float* b2b   = (const float*)d_in[18];

    float* out   = (float*)d_out;
    float* alpha = out;                       // 12800
    float* h_seq = out + 12800;               // 1,638,400
    float* C_out = out + 12800 + 1638400;     // 25,600,000
    float* ws    = (float*)d_ws;

    hipLaunchKernelGGL(pre_kernel, dim3(144), dim3(512), 0, stream,
                       v_d, v_r, v_c, W_ih, W2a, ws);
    hipLaunchKernelGGL(fused_kernel, dim3(NGRU + BB), dim3(512), 0, stream,
                       c_seq, d_seq, r_seq, D_emb, W_hh, b_ih, b_hh,
                       W2b, b2a, b2b, ws, C_out, h_seq);
    hipLaunchKernelGGL(alpha_kernel, dim3(100), dim3(512), 0, stream,
                       h_seq, W1a, b1a, W1b, b1b, alpha);
}